// Round 1
// baseline (929.494 us; speedup 1.0000x reference)
//
#include <hip/hip_runtime.h>

#define NN 100000

// ---------------- CSR build ----------------

__global__ void hist_kernel(const int* __restrict__ dst, int E, int* __restrict__ cnt) {
    int e = blockIdx.x * blockDim.x + threadIdx.x;
    if (e < E) atomicAdd(&cnt[dst[e]], 1);
}

// block sums over 512-element chunks
__global__ void scan1_kernel(const int* __restrict__ cnt, int N, int* __restrict__ partials) {
    int t = threadIdx.x, b = blockIdx.x;
    int i0 = b * 512 + 2 * t;
    int a = (i0 < N) ? cnt[i0] : 0;
    int c = (i0 + 1 < N) ? cnt[i0 + 1] : 0;
    int s = a + c;
    for (int off = 32; off; off >>= 1) s += __shfl_down(s, off, 64);
    __shared__ int wsum[4];
    int lane = t & 63, wv = t >> 6;
    if (lane == 0) wsum[wv] = s;
    __syncthreads();
    if (t == 0) partials[b] = wsum[0] + wsum[1] + wsum[2] + wsum[3];
}

// single-block exclusive scan of partials (P <= 256)
__global__ void scan2_kernel(int* __restrict__ partials, int P, int* __restrict__ rowptr, int N, int E) {
    int t = threadIdx.x;
    __shared__ int sh[256];
    int v = (t < P) ? partials[t] : 0;
    sh[t] = v;
    __syncthreads();
    for (int off = 1; off < 256; off <<= 1) {
        int u = (t >= off) ? sh[t - off] : 0;
        __syncthreads();
        sh[t] += u;
        __syncthreads();
    }
    if (t < P) partials[t] = sh[t] - v;   // exclusive
    if (t == 0) rowptr[N] = E;
}

// per-chunk exclusive scan + write rowptr/fill/dinv
__global__ void scan3_kernel(const int* __restrict__ cnt, const int* __restrict__ partials, int N,
                             int* __restrict__ rowptr, int* __restrict__ fillp, float* __restrict__ dinv) {
    int t = threadIdx.x, b = blockIdx.x;
    int i0 = b * 512 + 2 * t;
    int a = (i0 < N) ? cnt[i0] : 0;
    int c = (i0 + 1 < N) ? cnt[i0 + 1] : 0;
    int s = a + c;
    __shared__ int sh[256];
    sh[t] = s;
    __syncthreads();
    for (int off = 1; off < 256; off <<= 1) {
        int u = (t >= off) ? sh[t - off] : 0;
        __syncthreads();
        sh[t] += u;
        __syncthreads();
    }
    int ex = sh[t] - s + partials[b];
    if (i0 < N) {
        rowptr[i0] = ex; fillp[i0] = ex;
        dinv[i0] = rsqrtf(1.0f + (float)a);
    }
    if (i0 + 1 < N) {
        int e1 = ex + a;
        rowptr[i0 + 1] = e1; fillp[i0 + 1] = e1;
        dinv[i0 + 1] = rsqrtf(1.0f + (float)c);
    }
}

__global__ void fill_kernel(const int* __restrict__ src, const int* __restrict__ dst, int E,
                            int* __restrict__ fillp, int* __restrict__ col) {
    int e = blockIdx.x * blockDim.x + threadIdx.x;
    if (e < E) {
        int d = dst[e];
        int p = atomicAdd(&fillp[d], 1);
        col[p] = src[e];
    }
}

// ---------------- GEMM: out[n,c] = sum_k X[n,k]*W[k,c]; optional row scale / col bias ----------------

template <int K, int C>
__global__ __launch_bounds__(256) void gemm_kernel(const float* __restrict__ X, const float* __restrict__ W,
                                                   const float* __restrict__ bias, const float* __restrict__ scale,
                                                   float* __restrict__ out, int N) {
    constexpr int MC = C / 16;          // cols per thread (C in {64,32,16} -> 4,2,1)
    constexpr int XS = K + 4;           // padded row stride (keeps 16B alignment, breaks bank conflicts)
    __shared__ float XL[64 * XS];
    __shared__ float WL[K * C];
    int t = threadIdx.x;
    int r0 = blockIdx.x * 64;

    for (int i = t; i < K * C / 4; i += 256)
        ((float4*)WL)[i] = ((const float4*)W)[i];

    constexpr int RV = K / 4;           // float4 per row
    for (int i = t; i < 64 * RV; i += 256) {
        int row = i / RV, c4 = i % RV;
        float4 v = make_float4(0.f, 0.f, 0.f, 0.f);
        if (r0 + row < N) v = ((const float4*)(X + (long)(r0 + row) * K))[c4];
        *(float4*)&XL[row * XS + c4 * 4] = v;
    }
    __syncthreads();

    int ty = t >> 4, tx = t & 15;
    float acc[4][MC];
    #pragma unroll
    for (int i = 0; i < 4; ++i)
        #pragma unroll
        for (int j = 0; j < MC; ++j) acc[i][j] = 0.f;

    const float* xb = &XL[(ty * 4) * XS];
    const float* wb = &WL[tx * MC];
    for (int k = 0; k < K; ++k) {
        float x0 = xb[k], x1 = xb[XS + k], x2 = xb[2 * XS + k], x3 = xb[3 * XS + k];
        float w[MC];
        #pragma unroll
        for (int j = 0; j < MC; ++j) w[j] = wb[k * C + j];
        #pragma unroll
        for (int j = 0; j < MC; ++j) {
            acc[0][j] = fmaf(x0, w[j], acc[0][j]);
            acc[1][j] = fmaf(x1, w[j], acc[1][j]);
            acc[2][j] = fmaf(x2, w[j], acc[2][j]);
            acc[3][j] = fmaf(x3, w[j], acc[3][j]);
        }
    }

    #pragma unroll
    for (int i = 0; i < 4; ++i) {
        int row = r0 + ty * 4 + i;
        if (row < N) {
            float sc = scale ? scale[row] : 1.0f;
            #pragma unroll
            for (int j = 0; j < MC; ++j) {
                int c = tx * MC + j;
                float v = acc[i][j] * sc;
                if (bias) v += bias[c];
                out[(long)row * C + c] = v;
            }
        }
    }
}

// ---------------- Aggregation: out = relu(dinv[i]*(sum_nbr hs[src] + hs[i]) + b) + skips ----------------

template <int F>
__global__ __launch_bounds__(256) void agg_kernel(const float* __restrict__ hs, const int* __restrict__ rowptr,
                                                  const int* __restrict__ col, const float* __restrict__ dinv,
                                                  const float* __restrict__ bias,
                                                  const float* __restrict__ skipA, const float* __restrict__ skipB,
                                                  float* __restrict__ out, int N) {
    int t = threadIdx.x;
    int lane = t & 63, wv = t >> 6;
    constexpr int NPW = 64 / F;         // nodes per wave
    int sub = lane / F, f = lane % F;
    int i = (blockIdx.x * 4 + wv) * NPW + sub;
    if (i >= N) return;

    float acc = hs[(long)i * F + f];    // self-loop term (hs already has dinv[src] folded in)
    int p0 = rowptr[i], p1 = rowptr[i + 1];
    for (int p = p0; p < p1; p += F) {
        int c = ((p + f) < p1) ? col[p + f] : 0;
        int m = min(F, p1 - p);
        #pragma unroll 4
        for (int k = 0; k < m; ++k) {
            int s = __shfl(c, k, F);
            acc += hs[(long)s * F + f];
        }
    }
    float v = fmaxf(dinv[i] * acc + bias[f], 0.0f);
    if (skipA) v += skipA[(long)i * F + f];
    if (skipB) v += skipB[(long)i * F + f];
    out[(long)i * F + f] = v;
}

// ---------------- launch ----------------

extern "C" void kernel_launch(void* const* d_in, const int* in_sizes, int n_in,
                              void* d_out, int out_size, void* d_ws, size_t ws_size,
                              hipStream_t stream) {
    const int N = NN;
    const float* x   = (const float*)d_in[0];
    const int*   ei  = (const int*)d_in[1];
    const int    E   = in_sizes[1] / 2;
    const int*   src = ei;
    const int*   dst = ei + E;
    const float* W1 = (const float*)d_in[2],  *b1  = (const float*)d_in[3];
    const float* W2 = (const float*)d_in[4],  *b2  = (const float*)d_in[5];
    const float* W3 = (const float*)d_in[6],  *b3  = (const float*)d_in[7];
    const float* Ws02 = (const float*)d_in[8],  *bs02 = (const float*)d_in[9];
    const float* Ws03 = (const float*)d_in[10], *bs03 = (const float*)d_in[11];
    const float* Ws13 = (const float*)d_in[12], *bs13 = (const float*)d_in[13];

    char* w = (char*)d_ws;
    size_t off = 0;
    auto alloc = [&](size_t bytes) -> void* {
        void* p = w + off;
        off += (bytes + 255) & ~(size_t)255;
        return p;
    };
    int*   cnt      = (int*)alloc((size_t)N * 4);
    int*   rowptr   = (int*)alloc(((size_t)N + 1) * 4);
    int*   fillp    = (int*)alloc((size_t)N * 4);
    int*   partials = (int*)alloc(256 * 4);
    float* dinv     = (float*)alloc((size_t)N * 4);
    int*   col      = (int*)alloc((size_t)E * 4);
    float* hs1      = (float*)alloc((size_t)N * 64 * 4);
    float* x1       = (float*)alloc((size_t)N * 64 * 4);
    float* s02      = (float*)alloc((size_t)N * 32 * 4);
    float* s03      = (float*)alloc((size_t)N * 16 * 4);
    float* x2       = (float*)alloc((size_t)N * 32 * 4);
    // reuse dead regions
    float* hs2 = hs1;              // after agg<64>, hs1 is dead
    float* s13 = hs1 + (size_t)N * 32;
    float* hs3 = s02;              // after agg<32>, s02 is dead

    hipMemsetAsync(cnt, 0, (size_t)N * 4, stream);
    hist_kernel<<<(E + 255) / 256, 256, 0, stream>>>(dst, E, cnt);
    int P = (N + 511) / 512;
    scan1_kernel<<<P, 256, 0, stream>>>(cnt, N, partials);
    scan2_kernel<<<1, 256, 0, stream>>>(partials, P, rowptr, N, E);
    scan3_kernel<<<P, 256, 0, stream>>>(cnt, partials, N, rowptr, fillp, dinv);
    fill_kernel<<<(E + 255) / 256, 256, 0, stream>>>(src, dst, E, fillp, col);

    int gb = (N + 63) / 64;
    // layer 1 GEMMs from x
    gemm_kernel<128, 64><<<gb, 256, 0, stream>>>(x, W1, nullptr, dinv, hs1, N);
    gemm_kernel<128, 32><<<gb, 256, 0, stream>>>(x, Ws02, bs02, nullptr, s02, N);
    gemm_kernel<128, 16><<<gb, 256, 0, stream>>>(x, Ws03, bs03, nullptr, s03, N);
    // agg 1 -> x1 = relu(...)
    agg_kernel<64><<<N / 4, 256, 0, stream>>>(hs1, rowptr, col, dinv, b1, nullptr, nullptr, x1, N);
    // layer 2 GEMMs from x1
    gemm_kernel<64, 32><<<gb, 256, 0, stream>>>(x1, W2, nullptr, dinv, hs2, N);
    gemm_kernel<64, 16><<<gb, 256, 0, stream>>>(x1, Ws13, bs13, nullptr, s13, N);
    // agg 2 -> x2 = relu(...) + s02
    agg_kernel<32><<<N / 8, 256, 0, stream>>>(hs2, rowptr, col, dinv, b2, s02, nullptr, x2, N);
    // layer 3 GEMM from x2
    gemm_kernel<32, 16><<<gb, 256, 0, stream>>>(x2, W3, nullptr, dinv, hs3, N);
    // agg 3 -> out = relu(...) + s03 + s13
    agg_kernel<16><<<N / 16, 256, 0, stream>>>(hs3, rowptr, col, dinv, b3, s03, s13, (float*)d_out, N);
}

// Round 2
// 610.637 us; speedup vs baseline: 1.5222x; 1.5222x over previous
//
#include <hip/hip_runtime.h>

#define NN 100000
#define NB 512            // buckets
#define NPB 196           // nodes per bucket: ceil(100000/512)=196; local dst fits in 8 bits

// ---------------- CSR build: 2-level bucket multisplit ----------------

// pass 1: bucket histogram (LDS-staged)
__global__ __launch_bounds__(256) void bcount_kernel(const int* __restrict__ dst, int E, int* __restrict__ bcnt) {
    __shared__ int h[NB];
    for (int i = threadIdx.x; i < NB; i += 256) h[i] = 0;
    __syncthreads();
    for (int e = blockIdx.x * 256 + threadIdx.x; e < E; e += gridDim.x * 256)
        atomicAdd(&h[dst[e] / NPB], 1);
    __syncthreads();
    for (int i = threadIdx.x; i < NB; i += 256)
        if (h[i]) atomicAdd(&bcnt[i], h[i]);
}

// pass 2: exclusive scan of 512 bucket counts (single block)
__global__ __launch_bounds__(512) void bscan_kernel(const int* __restrict__ bcnt, int* __restrict__ bstart,
                                                    int* __restrict__ cursors, int E) {
    __shared__ int sh[NB];
    int t = threadIdx.x;
    int v = bcnt[t];
    sh[t] = v;
    __syncthreads();
    for (int off = 1; off < NB; off <<= 1) {
        int u = (t >= off) ? sh[t - off] : 0;
        __syncthreads();
        sh[t] += u;
        __syncthreads();
    }
    int ex = sh[t] - v;
    bstart[t] = ex;
    cursors[t] = ex;
    if (t == NB - 1) bstart[NB] = E;
}

// pass 3: scatter packed (src<<8 | local_dst) into bucket-segmented regions.
// Block-local LDS count -> one global atomicAdd per bucket per chunk -> LDS-cursor scatter.
// 512 cursors each advance ~sequentially => line-dense writes (vs 100K hot cursors before).
__global__ __launch_bounds__(256) void multisplit_kernel(const int* __restrict__ src, const int* __restrict__ dst,
                                                         int E, int* __restrict__ cursors,
                                                         unsigned int* __restrict__ packed) {
    __shared__ int cnt[NB];
    __shared__ int base[NB];
    const int CH = 256 * 16;
    int t = threadIdx.x;
    for (long c0 = (long)blockIdx.x * CH; c0 < E; c0 += (long)gridDim.x * CH) {
        for (int i = t; i < NB; i += 256) cnt[i] = 0;
        __syncthreads();
        int s[16], d[16];
        #pragma unroll
        for (int k = 0; k < 16; ++k) {
            long e = c0 + k * 256 + t;
            if (e < E) {
                d[k] = dst[e];
                s[k] = src[e];
                atomicAdd(&cnt[d[k] / NPB], 1);
            } else d[k] = -1;
        }
        __syncthreads();
        for (int i = t; i < NB; i += 256)
            base[i] = cnt[i] ? atomicAdd(&cursors[i], cnt[i]) : 0;
        __syncthreads();
        #pragma unroll
        for (int k = 0; k < 16; ++k) {
            if (d[k] >= 0) {
                int b = d[k] / NPB;
                int ld = d[k] - b * NPB;
                int pos = atomicAdd(&base[b], 1);
                packed[pos] = ((unsigned int)s[k] << 8) | (unsigned int)ld;
            }
        }
        __syncthreads();
    }
}

// pass 4: per-bucket local CSR (one block per bucket): LDS hist + scan -> rowptr/dinv, LDS-cursor fill -> col
__global__ __launch_bounds__(256) void bucket_fill_kernel(const unsigned int* __restrict__ packed,
                                                          const int* __restrict__ bstart, int N, int E,
                                                          int* __restrict__ rowptr, int* __restrict__ col,
                                                          float* __restrict__ dinv) {
    int b = blockIdx.x, t = threadIdx.x;
    int e0 = bstart[b], e1 = bstart[b + 1];
    __shared__ int hist[256];
    __shared__ int sh[256];
    __shared__ int cur[256];
    hist[t] = 0;
    __syncthreads();
    for (int e = e0 + t; e < e1; e += 256)
        atomicAdd(&hist[packed[e] & 255u], 1);
    __syncthreads();
    int v = hist[t];
    sh[t] = v;
    __syncthreads();
    for (int off = 1; off < 256; off <<= 1) {
        int u = (t >= off) ? sh[t - off] : 0;
        __syncthreads();
        sh[t] += u;
        __syncthreads();
    }
    int ex = sh[t] - v;
    int node = b * NPB + t;
    if (t < NPB && node < N) {
        rowptr[node] = e0 + ex;
        dinv[node] = rsqrtf(1.0f + (float)v);
    }
    cur[t] = e0 + ex;
    __syncthreads();
    for (int e = e0 + t; e < e1; e += 256) {
        unsigned int p = packed[e];
        int pos = atomicAdd(&cur[p & 255u], 1);
        col[pos] = (int)(p >> 8);
    }
    if (b == 0 && t == 0) rowptr[N] = E;
}

// ---------------- GEMM: out[n,c] = sum_k X[n,k]*W[k,c]; optional row scale / col bias ----------------

template <int K, int C>
__global__ __launch_bounds__(256) void gemm_kernel(const float* __restrict__ X, const float* __restrict__ W,
                                                   const float* __restrict__ bias, const float* __restrict__ scale,
                                                   float* __restrict__ out, int N) {
    constexpr int MC = C / 16;
    constexpr int XS = K + 4;
    __shared__ float XL[64 * XS];
    __shared__ float WL[K * C];
    int t = threadIdx.x;
    int r0 = blockIdx.x * 64;

    for (int i = t; i < K * C / 4; i += 256)
        ((float4*)WL)[i] = ((const float4*)W)[i];

    constexpr int RV = K / 4;
    for (int i = t; i < 64 * RV; i += 256) {
        int row = i / RV, c4 = i % RV;
        float4 v = make_float4(0.f, 0.f, 0.f, 0.f);
        if (r0 + row < N) v = ((const float4*)(X + (long)(r0 + row) * K))[c4];
        *(float4*)&XL[row * XS + c4 * 4] = v;
    }
    __syncthreads();

    int ty = t >> 4, tx = t & 15;
    float acc[4][MC];
    #pragma unroll
    for (int i = 0; i < 4; ++i)
        #pragma unroll
        for (int j = 0; j < MC; ++j) acc[i][j] = 0.f;

    const float* xb = &XL[(ty * 4) * XS];
    const float* wb = &WL[tx * MC];
    for (int k = 0; k < K; ++k) {
        float x0 = xb[k], x1 = xb[XS + k], x2 = xb[2 * XS + k], x3 = xb[3 * XS + k];
        float w[MC];
        #pragma unroll
        for (int j = 0; j < MC; ++j) w[j] = wb[k * C + j];
        #pragma unroll
        for (int j = 0; j < MC; ++j) {
            acc[0][j] = fmaf(x0, w[j], acc[0][j]);
            acc[1][j] = fmaf(x1, w[j], acc[1][j]);
            acc[2][j] = fmaf(x2, w[j], acc[2][j]);
            acc[3][j] = fmaf(x3, w[j], acc[3][j]);
        }
    }

    #pragma unroll
    for (int i = 0; i < 4; ++i) {
        int row = r0 + ty * 4 + i;
        if (row < N) {
            float sc = scale ? scale[row] : 1.0f;
            #pragma unroll
            for (int j = 0; j < MC; ++j) {
                int c = tx * MC + j;
                float v = acc[i][j] * sc;
                if (bias) v += bias[c];
                out[(long)row * C + c] = v;
            }
        }
    }
}

// ---------------- Aggregation: out = relu(dinv[i]*(sum_nbr hs[src] + hs[i]) + b) + skips ----------------

template <int F>
__global__ __launch_bounds__(256) void agg_kernel(const float* __restrict__ hs, const int* __restrict__ rowptr,
                                                  const int* __restrict__ col, const float* __restrict__ dinv,
                                                  const float* __restrict__ bias,
                                                  const float* __restrict__ skipA, const float* __restrict__ skipB,
                                                  float* __restrict__ out, int N) {
    int t = threadIdx.x;
    int lane = t & 63, wv = t >> 6;
    constexpr int NPW = 64 / F;
    int sub = lane / F, f = lane % F;
    int i = (blockIdx.x * 4 + wv) * NPW + sub;
    if (i >= N) return;

    float acc = hs[(long)i * F + f];
    int p0 = rowptr[i], p1 = rowptr[i + 1];
    for (int p = p0; p < p1; p += F) {
        int c = ((p + f) < p1) ? col[p + f] : 0;
        int m = min(F, p1 - p);
        #pragma unroll 4
        for (int k = 0; k < m; ++k) {
            int s = __shfl(c, k, F);
            acc += hs[(long)s * F + f];
        }
    }
    float v = fmaxf(dinv[i] * acc + bias[f], 0.0f);
    if (skipA) v += skipA[(long)i * F + f];
    if (skipB) v += skipB[(long)i * F + f];
    out[(long)i * F + f] = v;
}

// ---------------- launch ----------------

extern "C" void kernel_launch(void* const* d_in, const int* in_sizes, int n_in,
                              void* d_out, int out_size, void* d_ws, size_t ws_size,
                              hipStream_t stream) {
    const int N = NN;
    const float* x   = (const float*)d_in[0];
    const int*   ei  = (const int*)d_in[1];
    const int    E   = in_sizes[1] / 2;
    const int*   src = ei;
    const int*   dst = ei + E;
    const float* W1 = (const float*)d_in[2],  *b1  = (const float*)d_in[3];
    const float* W2 = (const float*)d_in[4],  *b2  = (const float*)d_in[5];
    const float* W3 = (const float*)d_in[6],  *b3  = (const float*)d_in[7];
    const float* Ws02 = (const float*)d_in[8],  *bs02 = (const float*)d_in[9];
    const float* Ws03 = (const float*)d_in[10], *bs03 = (const float*)d_in[11];
    const float* Ws13 = (const float*)d_in[12], *bs13 = (const float*)d_in[13];

    char* w = (char*)d_ws;
    size_t off = 0;
    auto alloc = [&](size_t bytes) -> void* {
        void* p = w + off;
        off += (bytes + 255) & ~(size_t)255;
        return p;
    };
    int*   bcnt     = (int*)alloc((size_t)NB * 4);
    int*   bstart   = (int*)alloc((size_t)(NB + 1) * 4);
    int*   cursors  = (int*)alloc((size_t)NB * 4);
    int*   rowptr   = (int*)alloc(((size_t)N + 1) * 4);
    float* dinv     = (float*)alloc((size_t)N * 4);
    int*   col      = (int*)alloc((size_t)E * 4);
    float* hs1      = (float*)alloc((size_t)N * 64 * 4);
    float* x1       = (float*)alloc((size_t)N * 64 * 4);
    float* s02      = (float*)alloc((size_t)N * 32 * 4);
    float* s03      = (float*)alloc((size_t)N * 16 * 4);
    float* x2       = (float*)alloc((size_t)N * 32 * 4);
    // aliases over dead regions
    unsigned int* packed = (unsigned int*)x1;   // dead before agg1 writes x1
    float* hs2 = hs1;                           // after agg<64>, hs1 is dead
    float* s13 = hs1 + (size_t)N * 32;
    float* hs3 = s02;                           // after agg<32>, s02 is dead

    // ---- CSR build ----
    hipMemsetAsync(bcnt, 0, (size_t)NB * 4, stream);
    bcount_kernel<<<1024, 256, 0, stream>>>(dst, E, bcnt);
    bscan_kernel<<<1, NB, 0, stream>>>(bcnt, bstart, cursors, E);
    multisplit_kernel<<<(E + 4095) / 4096, 256, 0, stream>>>(src, dst, E, cursors, packed);
    bucket_fill_kernel<<<NB, 256, 0, stream>>>(packed, bstart, N, E, rowptr, col, dinv);

    int gb = (N + 63) / 64;
    // layer 1 GEMMs from x
    gemm_kernel<128, 64><<<gb, 256, 0, stream>>>(x, W1, nullptr, dinv, hs1, N);
    gemm_kernel<128, 32><<<gb, 256, 0, stream>>>(x, Ws02, bs02, nullptr, s02, N);
    gemm_kernel<128, 16><<<gb, 256, 0, stream>>>(x, Ws03, bs03, nullptr, s03, N);
    // agg 1 -> x1 = relu(...)
    agg_kernel<64><<<N / 4, 256, 0, stream>>>(hs1, rowptr, col, dinv, b1, nullptr, nullptr, x1, N);
    // layer 2 GEMMs from x1
    gemm_kernel<64, 32><<<gb, 256, 0, stream>>>(x1, W2, nullptr, dinv, hs2, N);
    gemm_kernel<64, 16><<<gb, 256, 0, stream>>>(x1, Ws13, bs13, nullptr, s13, N);
    // agg 2 -> x2 = relu(...) + s02
    agg_kernel<32><<<N / 8, 256, 0, stream>>>(hs2, rowptr, col, dinv, b2, s02, nullptr, x2, N);
    // layer 3 GEMM from x2
    gemm_kernel<32, 16><<<gb, 256, 0, stream>>>(x2, W3, nullptr, dinv, hs3, N);
    // agg 3 -> out = relu(...) + s03 + s13
    agg_kernel<16><<<N / 16, 256, 0, stream>>>(hs3, rowptr, col, dinv, b3, s03, s13, (float*)d_out, N);
}

// Round 3
// 412.013 us; speedup vs baseline: 2.2560x; 1.4821x over previous
//
#include <hip/hip_runtime.h>

#define NN 100000
#define NB 512            // buckets
#define NPB 196           // nodes per bucket: ceil(100000/512)=196; local dst fits in 8 bits

__device__ inline unsigned short f2bf(float f) {
    unsigned u = __float_as_uint(f);
    unsigned r = (u + 0x7FFFu + ((u >> 16) & 1u)) >> 16;
    return (unsigned short)r;
}
__device__ inline float bf2f(unsigned short h) { return __uint_as_float((unsigned)h << 16); }

// ---------------- CSR build: 2-level bucket multisplit ----------------

__global__ __launch_bounds__(256) void bcount_kernel(const int* __restrict__ dst, int E, int* __restrict__ bcnt) {
    __shared__ int h[NB];
    for (int i = threadIdx.x; i < NB; i += 256) h[i] = 0;
    __syncthreads();
    for (int e = blockIdx.x * 256 + threadIdx.x; e < E; e += gridDim.x * 256)
        atomicAdd(&h[dst[e] / NPB], 1);
    __syncthreads();
    for (int i = threadIdx.x; i < NB; i += 256)
        if (h[i]) atomicAdd(&bcnt[i], h[i]);
}

__global__ __launch_bounds__(512) void bscan_kernel(const int* __restrict__ bcnt, int* __restrict__ bstart,
                                                    int* __restrict__ cursors, int E) {
    __shared__ int sh[NB];
    int t = threadIdx.x;
    int v = bcnt[t];
    sh[t] = v;
    __syncthreads();
    for (int off = 1; off < NB; off <<= 1) {
        int u = (t >= off) ? sh[t - off] : 0;
        __syncthreads();
        sh[t] += u;
        __syncthreads();
    }
    int ex = sh[t] - v;
    bstart[t] = ex;
    cursors[t] = ex;
    if (t == NB - 1) bstart[NB] = E;
}

__global__ __launch_bounds__(256) void multisplit_kernel(const int* __restrict__ src, const int* __restrict__ dst,
                                                         int E, int* __restrict__ cursors,
                                                         unsigned int* __restrict__ packed) {
    __shared__ int cnt[NB];
    __shared__ int base[NB];
    const int CH = 256 * 16;
    int t = threadIdx.x;
    for (long c0 = (long)blockIdx.x * CH; c0 < E; c0 += (long)gridDim.x * CH) {
        for (int i = t; i < NB; i += 256) cnt[i] = 0;
        __syncthreads();
        int s[16], d[16];
        #pragma unroll
        for (int k = 0; k < 16; ++k) {
            long e = c0 + k * 256 + t;
            if (e < E) {
                d[k] = dst[e];
                s[k] = src[e];
                atomicAdd(&cnt[d[k] / NPB], 1);
            } else d[k] = -1;
        }
        __syncthreads();
        for (int i = t; i < NB; i += 256)
            base[i] = cnt[i] ? atomicAdd(&cursors[i], cnt[i]) : 0;
        __syncthreads();
        #pragma unroll
        for (int k = 0; k < 16; ++k) {
            if (d[k] >= 0) {
                int b = d[k] / NPB;
                int ld = d[k] - b * NPB;
                int pos = atomicAdd(&base[b], 1);
                packed[pos] = ((unsigned int)s[k] << 8) | (unsigned int)ld;
            }
        }
        __syncthreads();
    }
}

__global__ __launch_bounds__(256) void bucket_fill_kernel(const unsigned int* __restrict__ packed,
                                                          const int* __restrict__ bstart, int N, int E,
                                                          int* __restrict__ rowptr, int* __restrict__ col,
                                                          float* __restrict__ dinv) {
    int b = blockIdx.x, t = threadIdx.x;
    int e0 = bstart[b], e1 = bstart[b + 1];
    __shared__ int hist[256];
    __shared__ int sh[256];
    __shared__ int cur[256];
    hist[t] = 0;
    __syncthreads();
    for (int e = e0 + t; e < e1; e += 256)
        atomicAdd(&hist[packed[e] & 255u], 1);
    __syncthreads();
    int v = hist[t];
    sh[t] = v;
    __syncthreads();
    for (int off = 1; off < 256; off <<= 1) {
        int u = (t >= off) ? sh[t - off] : 0;
        __syncthreads();
        sh[t] += u;
        __syncthreads();
    }
    int ex = sh[t] - v;
    int node = b * NPB + t;
    if (t < NPB && node < N) {
        rowptr[node] = e0 + ex;
        dinv[node] = rsqrtf(1.0f + (float)v);
    }
    cur[t] = e0 + ex;
    __syncthreads();
    for (int e = e0 + t; e < e1; e += 256) {
        unsigned int p = packed[e];
        int pos = atomicAdd(&cur[p & 255u], 1);
        col[pos] = (int)(p >> 8);
    }
    if (b == 0 && t == 0) rowptr[N] = E;
}

// ---------------- GEMM: out[n,c] = sum_k X[n,k]*W[k,c]; optional row scale / col bias ----------------
// OBF: write output as bf16 (for the gather-consumed hs matrices)

template <int K, int C, bool OBF>
__global__ __launch_bounds__(256) void gemm_kernel(const float* __restrict__ X, const float* __restrict__ W,
                                                   const float* __restrict__ bias, const float* __restrict__ scale,
                                                   void* __restrict__ outv, int N) {
    constexpr int MC = C / 16;
    constexpr int XS = K + 4;
    __shared__ float XL[64 * XS];
    __shared__ float WL[K * C];
    int t = threadIdx.x;
    int r0 = blockIdx.x * 64;

    for (int i = t; i < K * C / 4; i += 256)
        ((float4*)WL)[i] = ((const float4*)W)[i];

    constexpr int RV = K / 4;
    for (int i = t; i < 64 * RV; i += 256) {
        int row = i / RV, c4 = i % RV;
        float4 v = make_float4(0.f, 0.f, 0.f, 0.f);
        if (r0 + row < N) v = ((const float4*)(X + (long)(r0 + row) * K))[c4];
        *(float4*)&XL[row * XS + c4 * 4] = v;
    }
    __syncthreads();

    int ty = t >> 4, tx = t & 15;
    float acc[4][MC];
    #pragma unroll
    for (int i = 0; i < 4; ++i)
        #pragma unroll
        for (int j = 0; j < MC; ++j) acc[i][j] = 0.f;

    const float* xb = &XL[(ty * 4) * XS];
    const float* wb = &WL[tx * MC];
    for (int k = 0; k < K; ++k) {
        float x0 = xb[k], x1 = xb[XS + k], x2 = xb[2 * XS + k], x3 = xb[3 * XS + k];
        float w[MC];
        #pragma unroll
        for (int j = 0; j < MC; ++j) w[j] = wb[k * C + j];
        #pragma unroll
        for (int j = 0; j < MC; ++j) {
            acc[0][j] = fmaf(x0, w[j], acc[0][j]);
            acc[1][j] = fmaf(x1, w[j], acc[1][j]);
            acc[2][j] = fmaf(x2, w[j], acc[2][j]);
            acc[3][j] = fmaf(x3, w[j], acc[3][j]);
        }
    }

    #pragma unroll
    for (int i = 0; i < 4; ++i) {
        int row = r0 + ty * 4 + i;
        if (row < N) {
            float sc = scale ? scale[row] : 1.0f;
            #pragma unroll
            for (int j = 0; j < MC; ++j) {
                int c = tx * MC + j;
                float v = acc[i][j] * sc;
                if (bias) v += bias[c];
                if (OBF) ((unsigned short*)outv)[(long)row * C + c] = f2bf(v);
                else     ((float*)outv)[(long)row * C + c] = v;
            }
        }
    }
}

// ---------------- Aggregation: out = relu(dinv[i]*(sum_nbr hs[src] + hs[i]) + b) + skips ----------------
// hs is bf16 (dinv[src] pre-folded); accumulate fp32; 8-wide unrolled gather, 4 acc chains.

template <int F>
__global__ __launch_bounds__(256) void agg_kernel(const unsigned short* __restrict__ hs,
                                                  const int* __restrict__ rowptr,
                                                  const int* __restrict__ col, const float* __restrict__ dinv,
                                                  const float* __restrict__ bias,
                                                  const float* __restrict__ skipA, const float* __restrict__ skipB,
                                                  float* __restrict__ out, int N) {
    int t = threadIdx.x;
    int lane = t & 63, wv = t >> 6;
    constexpr int NPW = 64 / F;
    int sub = lane / F, f = lane % F;
    int i = (blockIdx.x * 4 + wv) * NPW + sub;
    if (i >= N) return;

    float a0 = bf2f(hs[(long)i * F + f]);   // self-loop term
    float a1 = 0.f, a2 = 0.f, a3 = 0.f;
    int p0 = rowptr[i], p1 = rowptr[i + 1];
    for (int p = p0; p < p1; p += F) {
        int c = ((p + f) < p1) ? col[p + f] : 0;
        int m = min(F, p1 - p);
        int k = 0;
        for (; k + 8 <= m; k += 8) {
            int s0 = __shfl(c, k + 0, F), s1 = __shfl(c, k + 1, F);
            int s2 = __shfl(c, k + 2, F), s3 = __shfl(c, k + 3, F);
            int s4 = __shfl(c, k + 4, F), s5 = __shfl(c, k + 5, F);
            int s6 = __shfl(c, k + 6, F), s7 = __shfl(c, k + 7, F);
            float v0 = bf2f(hs[(long)s0 * F + f]);
            float v1 = bf2f(hs[(long)s1 * F + f]);
            float v2 = bf2f(hs[(long)s2 * F + f]);
            float v3 = bf2f(hs[(long)s3 * F + f]);
            float v4 = bf2f(hs[(long)s4 * F + f]);
            float v5 = bf2f(hs[(long)s5 * F + f]);
            float v6 = bf2f(hs[(long)s6 * F + f]);
            float v7 = bf2f(hs[(long)s7 * F + f]);
            a0 += v0; a1 += v1; a2 += v2; a3 += v3;
            a0 += v4; a1 += v5; a2 += v6; a3 += v7;
        }
        for (; k < m; ++k) {
            int s = __shfl(c, k, F);
            a1 += bf2f(hs[(long)s * F + f]);
        }
    }
    float v = fmaxf(dinv[i] * ((a0 + a1) + (a2 + a3)) + bias[f], 0.0f);
    if (skipA) v += skipA[(long)i * F + f];
    if (skipB) v += skipB[(long)i * F + f];
    out[(long)i * F + f] = v;
}

// ---------------- launch ----------------

extern "C" void kernel_launch(void* const* d_in, const int* in_sizes, int n_in,
                              void* d_out, int out_size, void* d_ws, size_t ws_size,
                              hipStream_t stream) {
    const int N = NN;
    const float* x   = (const float*)d_in[0];
    const int*   ei  = (const int*)d_in[1];
    const int    E   = in_sizes[1] / 2;
    const int*   src = ei;
    const int*   dst = ei + E;
    const float* W1 = (const float*)d_in[2],  *b1  = (const float*)d_in[3];
    const float* W2 = (const float*)d_in[4],  *b2  = (const float*)d_in[5];
    const float* W3 = (const float*)d_in[6],  *b3  = (const float*)d_in[7];
    const float* Ws02 = (const float*)d_in[8],  *bs02 = (const float*)d_in[9];
    const float* Ws03 = (const float*)d_in[10], *bs03 = (const float*)d_in[11];
    const float* Ws13 = (const float*)d_in[12], *bs13 = (const float*)d_in[13];

    char* w = (char*)d_ws;
    size_t off = 0;
    auto alloc = [&](size_t bytes) -> void* {
        void* p = w + off;
        off += (bytes + 255) & ~(size_t)255;
        return p;
    };
    int*   bcnt     = (int*)alloc((size_t)NB * 4);
    int*   bstart   = (int*)alloc((size_t)(NB + 1) * 4);
    int*   cursors  = (int*)alloc((size_t)NB * 4);
    int*   rowptr   = (int*)alloc(((size_t)N + 1) * 4);
    float* dinv     = (float*)alloc((size_t)N * 4);
    int*   col      = (int*)alloc((size_t)E * 4);
    unsigned short* hs1 = (unsigned short*)alloc((size_t)N * 64 * 2);   // bf16
    float* x1       = (float*)alloc((size_t)N * 64 * 4);
    float* s02      = (float*)alloc((size_t)N * 32 * 4);
    float* s03      = (float*)alloc((size_t)N * 16 * 4);
    float* x2       = (float*)alloc((size_t)N * 32 * 4);
    // aliases over dead regions
    unsigned int* packed = (unsigned int*)x1;                    // dead before agg1 writes x1
    unsigned short* hs2 = hs1;                                   // after agg<64>, hs1 dead; needs N*32*2
    float* s13 = (float*)(hs1 + (size_t)N * 32);                 // second half of hs1 region: N*16 fp32
    unsigned short* hs3 = (unsigned short*)s02;                  // after agg<32>, s02 dead; needs N*16*2

    // ---- CSR build ----
    hipMemsetAsync(bcnt, 0, (size_t)NB * 4, stream);
    bcount_kernel<<<1024, 256, 0, stream>>>(dst, E, bcnt);
    bscan_kernel<<<1, NB, 0, stream>>>(bcnt, bstart, cursors, E);
    multisplit_kernel<<<(E + 4095) / 4096, 256, 0, stream>>>(src, dst, E, cursors, packed);
    bucket_fill_kernel<<<NB, 256, 0, stream>>>(packed, bstart, N, E, rowptr, col, dinv);

    int gb = (N + 63) / 64;
    // layer 1 GEMMs from x
    gemm_kernel<128, 64, true ><<<gb, 256, 0, stream>>>(x, W1, nullptr, dinv, hs1, N);
    gemm_kernel<128, 32, false><<<gb, 256, 0, stream>>>(x, Ws02, bs02, nullptr, s02, N);
    gemm_kernel<128, 16, false><<<gb, 256, 0, stream>>>(x, Ws03, bs03, nullptr, s03, N);
    // agg 1 -> x1 = relu(...)
    agg_kernel<64><<<N / 4, 256, 0, stream>>>(hs1, rowptr, col, dinv, b1, nullptr, nullptr, x1, N);
    // layer 2 GEMMs from x1
    gemm_kernel<64, 32, true ><<<gb, 256, 0, stream>>>(x1, W2, nullptr, dinv, hs2, N);
    gemm_kernel<64, 16, false><<<gb, 256, 0, stream>>>(x1, Ws13, bs13, nullptr, s13, N);
    // agg 2 -> x2 = relu(...) + s02
    agg_kernel<32><<<N / 8, 256, 0, stream>>>(hs2, rowptr, col, dinv, b2, s02, nullptr, x2, N);
    // layer 3 GEMM from x2
    gemm_kernel<32, 16, true ><<<gb, 256, 0, stream>>>(x2, W3, nullptr, dinv, hs3, N);
    // agg 3 -> out = relu(...) + s03 + s13
    agg_kernel<16><<<N / 16, 256, 0, stream>>>(hs3, rowptr, col, dinv, b3, s03, s13, (float*)d_out, N);
}

// Round 4
// 347.471 us; speedup vs baseline: 2.6750x; 1.1857x over previous
//
#include <hip/hip_runtime.h>

#define NN 100000
#define NB 512            // buckets
#define NPB 196           // nodes per bucket: ceil(100000/512)=196; local dst fits in 8 bits

__device__ inline unsigned short f2bf(float f) {
    unsigned u = __float_as_uint(f);
    unsigned r = (u + 0x7FFFu + ((u >> 16) & 1u)) >> 16;
    return (unsigned short)r;
}
__device__ inline float bf2f(unsigned short h) { return __uint_as_float((unsigned)h << 16); }

// accumulate 4 bf16 (packed in uint2) into float4
__device__ inline void bfacc(uint2 u, float4& a) {
    a.x += __uint_as_float(u.x << 16);
    a.y += __uint_as_float(u.x & 0xFFFF0000u);
    a.z += __uint_as_float(u.y << 16);
    a.w += __uint_as_float(u.y & 0xFFFF0000u);
}

// ---------------- CSR build: 2-level bucket multisplit ----------------

__global__ __launch_bounds__(256) void bcount_kernel(const int* __restrict__ dst, int E, int* __restrict__ bcnt) {
    __shared__ int h[NB];
    for (int i = threadIdx.x; i < NB; i += 256) h[i] = 0;
    __syncthreads();
    for (int e = blockIdx.x * 256 + threadIdx.x; e < E; e += gridDim.x * 256)
        atomicAdd(&h[dst[e] / NPB], 1);
    __syncthreads();
    for (int i = threadIdx.x; i < NB; i += 256)
        if (h[i]) atomicAdd(&bcnt[i], h[i]);
}

__global__ __launch_bounds__(512) void bscan_kernel(const int* __restrict__ bcnt, int* __restrict__ bstart,
                                                    int* __restrict__ cursors, int E) {
    __shared__ int sh[NB];
    int t = threadIdx.x;
    int v = bcnt[t];
    sh[t] = v;
    __syncthreads();
    for (int off = 1; off < NB; off <<= 1) {
        int u = (t >= off) ? sh[t - off] : 0;
        __syncthreads();
        sh[t] += u;
        __syncthreads();
    }
    int ex = sh[t] - v;
    bstart[t] = ex;
    cursors[t] = ex;
    if (t == NB - 1) bstart[NB] = E;
}

__global__ __launch_bounds__(256) void multisplit_kernel(const int* __restrict__ src, const int* __restrict__ dst,
                                                         int E, int* __restrict__ cursors,
                                                         unsigned int* __restrict__ packed) {
    __shared__ int cnt[NB];
    __shared__ int base[NB];
    const int CH = 256 * 16;
    int t = threadIdx.x;
    for (long c0 = (long)blockIdx.x * CH; c0 < E; c0 += (long)gridDim.x * CH) {
        for (int i = t; i < NB; i += 256) cnt[i] = 0;
        __syncthreads();
        int s[16], d[16];
        #pragma unroll
        for (int k = 0; k < 16; ++k) {
            long e = c0 + k * 256 + t;
            if (e < E) {
                d[k] = dst[e];
                s[k] = src[e];
                atomicAdd(&cnt[d[k] / NPB], 1);
            } else d[k] = -1;
        }
        __syncthreads();
        for (int i = t; i < NB; i += 256)
            base[i] = cnt[i] ? atomicAdd(&cursors[i], cnt[i]) : 0;
        __syncthreads();
        #pragma unroll
        for (int k = 0; k < 16; ++k) {
            if (d[k] >= 0) {
                int b = d[k] / NPB;
                int ld = d[k] - b * NPB;
                int pos = atomicAdd(&base[b], 1);
                packed[pos] = ((unsigned int)s[k] << 8) | (unsigned int)ld;
            }
        }
        __syncthreads();
    }
}

__global__ __launch_bounds__(256) void bucket_fill_kernel(const unsigned int* __restrict__ packed,
                                                          const int* __restrict__ bstart, int N, int E,
                                                          int* __restrict__ rowptr, int* __restrict__ col,
                                                          float* __restrict__ dinv) {
    int b = blockIdx.x, t = threadIdx.x;
    int e0 = bstart[b], e1 = bstart[b + 1];
    __shared__ int hist[256];
    __shared__ int sh[256];
    __shared__ int cur[256];
    hist[t] = 0;
    __syncthreads();
    for (int e = e0 + t; e < e1; e += 256)
        atomicAdd(&hist[packed[e] & 255u], 1);
    __syncthreads();
    int v = hist[t];
    sh[t] = v;
    __syncthreads();
    for (int off = 1; off < 256; off <<= 1) {
        int u = (t >= off) ? sh[t - off] : 0;
        __syncthreads();
        sh[t] += u;
        __syncthreads();
    }
    int ex = sh[t] - v;
    int node = b * NPB + t;
    if (t < NPB && node < N) {
        rowptr[node] = e0 + ex;
        dinv[node] = rsqrtf(1.0f + (float)v);
    }
    cur[t] = e0 + ex;
    __syncthreads();
    for (int e = e0 + t; e < e1; e += 256) {
        unsigned int p = packed[e];
        int pos = atomicAdd(&cur[p & 255u], 1);
        col[pos] = (int)(p >> 8);
    }
    if (b == 0 && t == 0) rowptr[N] = E;
}

// ---------------- GEMM (single output) ----------------

template <int K, int C, bool OBF>
__global__ __launch_bounds__(256) void gemm_kernel(const float* __restrict__ X, const float* __restrict__ W,
                                                   const float* __restrict__ bias, const float* __restrict__ scale,
                                                   void* __restrict__ outv, int N) {
    constexpr int MC = C / 16;
    constexpr int XS = K + 4;
    __shared__ float XL[64 * XS];
    __shared__ float WL[K * C];
    int t = threadIdx.x;
    int r0 = blockIdx.x * 64;

    for (int i = t; i < K * C / 4; i += 256)
        ((float4*)WL)[i] = ((const float4*)W)[i];

    constexpr int RV = K / 4;
    for (int i = t; i < 64 * RV; i += 256) {
        int row = i / RV, c4 = i % RV;
        float4 v = make_float4(0.f, 0.f, 0.f, 0.f);
        if (r0 + row < N) v = ((const float4*)(X + (long)(r0 + row) * K))[c4];
        *(float4*)&XL[row * XS + c4 * 4] = v;
    }
    __syncthreads();

    int ty = t >> 4, tx = t & 15;
    float acc[4][MC];
    #pragma unroll
    for (int i = 0; i < 4; ++i)
        #pragma unroll
        for (int j = 0; j < MC; ++j) acc[i][j] = 0.f;

    const float* xb = &XL[(ty * 4) * XS];
    const float* wb = &WL[tx * MC];
    for (int k = 0; k < K; ++k) {
        float x0 = xb[k], x1 = xb[XS + k], x2 = xb[2 * XS + k], x3 = xb[3 * XS + k];
        float w[MC];
        #pragma unroll
        for (int j = 0; j < MC; ++j) w[j] = wb[k * C + j];
        #pragma unroll
        for (int j = 0; j < MC; ++j) {
            acc[0][j] = fmaf(x0, w[j], acc[0][j]);
            acc[1][j] = fmaf(x1, w[j], acc[1][j]);
            acc[2][j] = fmaf(x2, w[j], acc[2][j]);
            acc[3][j] = fmaf(x3, w[j], acc[3][j]);
        }
    }

    #pragma unroll
    for (int i = 0; i < 4; ++i) {
        int row = r0 + ty * 4 + i;
        if (row < N) {
            float sc = scale ? scale[row] : 1.0f;
            #pragma unroll
            for (int j = 0; j < MC; ++j) {
                int c = tx * MC + j;
                float v = acc[i][j] * sc;
                if (bias) v += bias[c];
                if (OBF) ((unsigned short*)outv)[(long)row * C + c] = f2bf(v);
                else     ((float*)outv)[(long)row * C + c] = v;
            }
        }
    }
}

// ---------------- GEMM (two outputs sharing one X pass) ----------------
// out a: C1 cols, optional row scale, optional bias, bf16 if OBF1; out b: C2 cols, bias, fp32.

template <int K, int C1, int C2, bool OBF1>
__global__ __launch_bounds__(256) void gemm2_kernel(const float* __restrict__ X,
                                                    const float* __restrict__ Wa, const float* __restrict__ ba,
                                                    const float* __restrict__ scale,
                                                    const float* __restrict__ Wb, const float* __restrict__ bb,
                                                    void* __restrict__ outa, float* __restrict__ outb, int N) {
    constexpr int M1 = C1 / 16, M2 = C2 / 16;
    constexpr int XS = K + 4;
    __shared__ float XL[64 * XS];
    __shared__ float WLa[K * C1];
    __shared__ float WLb[K * C2];
    int t = threadIdx.x;
    int r0 = blockIdx.x * 64;

    for (int i = t; i < K * C1 / 4; i += 256) ((float4*)WLa)[i] = ((const float4*)Wa)[i];
    for (int i = t; i < K * C2 / 4; i += 256) ((float4*)WLb)[i] = ((const float4*)Wb)[i];

    constexpr int RV = K / 4;
    for (int i = t; i < 64 * RV; i += 256) {
        int row = i / RV, c4 = i % RV;
        float4 v = make_float4(0.f, 0.f, 0.f, 0.f);
        if (r0 + row < N) v = ((const float4*)(X + (long)(r0 + row) * K))[c4];
        *(float4*)&XL[row * XS + c4 * 4] = v;
    }
    __syncthreads();

    int ty = t >> 4, tx = t & 15;
    float acc1[4][M1], acc2[4][M2];
    #pragma unroll
    for (int i = 0; i < 4; ++i) {
        #pragma unroll
        for (int j = 0; j < M1; ++j) acc1[i][j] = 0.f;
        #pragma unroll
        for (int j = 0; j < M2; ++j) acc2[i][j] = 0.f;
    }

    const float* xb = &XL[(ty * 4) * XS];
    const float* wba = &WLa[tx * M1];
    const float* wbb = &WLb[tx * M2];
    for (int k = 0; k < K; ++k) {
        float x0 = xb[k], x1 = xb[XS + k], x2 = xb[2 * XS + k], x3 = xb[3 * XS + k];
        float wa[M1], wb2[M2];
        #pragma unroll
        for (int j = 0; j < M1; ++j) wa[j] = wba[k * C1 + j];
        #pragma unroll
        for (int j = 0; j < M2; ++j) wb2[j] = wbb[k * C2 + j];
        #pragma unroll
        for (int j = 0; j < M1; ++j) {
            acc1[0][j] = fmaf(x0, wa[j], acc1[0][j]);
            acc1[1][j] = fmaf(x1, wa[j], acc1[1][j]);
            acc1[2][j] = fmaf(x2, wa[j], acc1[2][j]);
            acc1[3][j] = fmaf(x3, wa[j], acc1[3][j]);
        }
        #pragma unroll
        for (int j = 0; j < M2; ++j) {
            acc2[0][j] = fmaf(x0, wb2[j], acc2[0][j]);
            acc2[1][j] = fmaf(x1, wb2[j], acc2[1][j]);
            acc2[2][j] = fmaf(x2, wb2[j], acc2[2][j]);
            acc2[3][j] = fmaf(x3, wb2[j], acc2[3][j]);
        }
    }

    #pragma unroll
    for (int i = 0; i < 4; ++i) {
        int row = r0 + ty * 4 + i;
        if (row < N) {
            float sc = scale ? scale[row] : 1.0f;
            #pragma unroll
            for (int j = 0; j < M1; ++j) {
                int c = tx * M1 + j;
                float v = acc1[i][j] * sc;
                if (ba) v += ba[c];
                if (OBF1) ((unsigned short*)outa)[(long)row * C1 + c] = f2bf(v);
                else      ((float*)outa)[(long)row * C1 + c] = v;
            }
            #pragma unroll
            for (int j = 0; j < M2; ++j) {
                int c = tx * M2 + j;
                outb[(long)row * C2 + c] = acc2[i][j] + bb[c];
            }
        }
    }
}

// ---------------- Aggregation ----------------
// out = relu(dinv[i]*(sum_nbr hs[src] + hs[i]) + b) + skips; hs bf16 with dinv[src] folded.
// Each lane loads uint2 = 4 bf16 (8B); VL=F/4 lanes per row; NPW=64/VL edges in flight per wave.

template <int F>
__global__ __launch_bounds__(256) void agg_kernel(const unsigned short* __restrict__ hs,
                                                  const int* __restrict__ rowptr,
                                                  const int* __restrict__ col, const float* __restrict__ dinv,
                                                  const float* __restrict__ bias,
                                                  const float* __restrict__ skipA, const float* __restrict__ skipB,
                                                  float* __restrict__ out, int N) {
    constexpr int VL = F / 4;           // lanes per row
    constexpr int NPW = 64 / VL;        // nodes per wave
    constexpr int RW = F / 4;           // uint2 per row
    int t = threadIdx.x;
    int lane = t & 63, wv = t >> 6;
    int sub = lane / VL, fq = lane % VL;
    int i = (blockIdx.x * 4 + wv) * NPW + sub;
    if (i >= N) return;

    const uint2* hv = (const uint2*)hs;
    float4 a0 = make_float4(0.f, 0.f, 0.f, 0.f);
    float4 a1 = make_float4(0.f, 0.f, 0.f, 0.f);
    bfacc(hv[(long)i * RW + fq], a0);   // self-loop term

    int p0 = rowptr[i], p1 = rowptr[i + 1];
    for (int p = p0; p < p1; p += VL) {
        int c = ((p + fq) < p1) ? col[p + fq] : 0;
        int m = min(VL, p1 - p);
        int k = 0;
        for (; k + 4 <= m; k += 4) {
            int s0 = __shfl(c, k + 0, VL), s1 = __shfl(c, k + 1, VL);
            int s2 = __shfl(c, k + 2, VL), s3 = __shfl(c, k + 3, VL);
            uint2 u0 = hv[(long)s0 * RW + fq];
            uint2 u1 = hv[(long)s1 * RW + fq];
            uint2 u2 = hv[(long)s2 * RW + fq];
            uint2 u3 = hv[(long)s3 * RW + fq];
            bfacc(u0, a0); bfacc(u1, a1); bfacc(u2, a0); bfacc(u3, a1);
        }
        for (; k < m; ++k) {
            int s = __shfl(c, k, VL);
            bfacc(hv[(long)s * RW + fq], a1);
        }
    }

    float4 acc = make_float4(a0.x + a1.x, a0.y + a1.y, a0.z + a1.z, a0.w + a1.w);
    float di = dinv[i];
    float4 b4 = *(const float4*)&bias[fq * 4];
    float4 v;
    v.x = fmaxf(di * acc.x + b4.x, 0.f);
    v.y = fmaxf(di * acc.y + b4.y, 0.f);
    v.z = fmaxf(di * acc.z + b4.z, 0.f);
    v.w = fmaxf(di * acc.w + b4.w, 0.f);
    if (skipA) {
        float4 s4 = *(const float4*)&skipA[(long)i * F + fq * 4];
        v.x += s4.x; v.y += s4.y; v.z += s4.z; v.w += s4.w;
    }
    if (skipB) {
        float4 s4 = *(const float4*)&skipB[(long)i * F + fq * 4];
        v.x += s4.x; v.y += s4.y; v.z += s4.z; v.w += s4.w;
    }
    *(float4*)&out[(long)i * F + fq * 4] = v;
}

// ---------------- launch ----------------

extern "C" void kernel_launch(void* const* d_in, const int* in_sizes, int n_in,
                              void* d_out, int out_size, void* d_ws, size_t ws_size,
                              hipStream_t stream) {
    const int N = NN;
    const float* x   = (const float*)d_in[0];
    const int*   ei  = (const int*)d_in[1];
    const int    E   = in_sizes[1] / 2;
    const int*   src = ei;
    const int*   dst = ei + E;
    const float* W1 = (const float*)d_in[2],  *b1  = (const float*)d_in[3];
    const float* W2 = (const float*)d_in[4],  *b2  = (const float*)d_in[5];
    const float* W3 = (const float*)d_in[6],  *b3  = (const float*)d_in[7];
    const float* Ws02 = (const float*)d_in[8],  *bs02 = (const float*)d_in[9];
    const float* Ws03 = (const float*)d_in[10], *bs03 = (const float*)d_in[11];
    const float* Ws13 = (const float*)d_in[12], *bs13 = (const float*)d_in[13];

    char* w = (char*)d_ws;
    size_t off = 0;
    auto alloc = [&](size_t bytes) -> void* {
        void* p = w + off;
        off += (bytes + 255) & ~(size_t)255;
        return p;
    };
    int*   bcnt     = (int*)alloc((size_t)NB * 4);
    int*   bstart   = (int*)alloc((size_t)(NB + 1) * 4);
    int*   cursors  = (int*)alloc((size_t)NB * 4);
    int*   rowptr   = (int*)alloc(((size_t)N + 1) * 4);
    float* dinv     = (float*)alloc((size_t)N * 4);
    int*   col      = (int*)alloc((size_t)E * 4);
    unsigned short* hs1 = (unsigned short*)alloc((size_t)N * 64 * 2);   // bf16
    float* x1       = (float*)alloc((size_t)N * 64 * 4);
    float* s02      = (float*)alloc((size_t)N * 32 * 4);
    float* s03      = (float*)alloc((size_t)N * 16 * 4);
    float* x2       = (float*)alloc((size_t)N * 32 * 4);
    // aliases over dead regions
    unsigned int* packed = (unsigned int*)x1;                    // dead before agg1 writes x1
    unsigned short* hs2 = hs1;                                   // after agg<64>, hs1 dead (N*32*2)
    float* s13 = (float*)(hs1 + (size_t)N * 32);                 // second half of hs1 region (N*16 fp32)
    unsigned short* hs3 = (unsigned short*)s02;                  // after agg<32>, s02 dead (N*16*2)

    // ---- CSR build ----
    hipMemsetAsync(bcnt, 0, (size_t)NB * 4, stream);
    bcount_kernel<<<1024, 256, 0, stream>>>(dst, E, bcnt);
    bscan_kernel<<<1, NB, 0, stream>>>(bcnt, bstart, cursors, E);
    multisplit_kernel<<<(E + 4095) / 4096, 256, 0, stream>>>(src, dst, E, cursors, packed);
    bucket_fill_kernel<<<NB, 256, 0, stream>>>(packed, bstart, N, E, rowptr, col, dinv);

    int gb = (N + 63) / 64;
    // layer 1: hs1 = dinv*(x@W1) [bf16]; {s02,s03} fused (one x pass)
    gemm_kernel<128, 64, true><<<gb, 256, 0, stream>>>(x, W1, nullptr, dinv, hs1, N);
    gemm2_kernel<128, 32, 16, false><<<gb, 256, 0, stream>>>(x, Ws02, bs02, nullptr, Ws03, bs03, s02, s03, N);
    // agg 1 -> x1
    agg_kernel<64><<<(N + 15) / 16, 256, 0, stream>>>(hs1, rowptr, col, dinv, b1, nullptr, nullptr, x1, N);
    // layer 2: {hs2 [bf16, scaled], s13} fused (one x1 pass)
    gemm2_kernel<64, 32, 16, true><<<gb, 256, 0, stream>>>(x1, W2, nullptr, dinv, Ws13, bs13, hs2, s13, N);
    // agg 2 -> x2
    agg_kernel<32><<<(N + 31) / 32, 256, 0, stream>>>(hs2, rowptr, col, dinv, b2, s02, nullptr, x2, N);
    // layer 3
    gemm_kernel<32, 16, true><<<gb, 256, 0, stream>>>(x2, W3, nullptr, dinv, hs3, N);
    // agg 3 -> out
    agg_kernel<16><<<(N + 63) / 64, 256, 0, stream>>>(hs3, rowptr, col, dinv, b3, s03, s13, (float*)d_out, N);
}